// Round 6
// baseline (221.579 us; speedup 1.0000x reference)
//
#include <hip/hip_runtime.h>

typedef __bf16 bf16x8 __attribute__((ext_vector_type(8)));
typedef __bf16 bf16x4 __attribute__((ext_vector_type(4)));
typedef float  f32x4  __attribute__((ext_vector_type(4)));

#define N_HEAD 12
#define HEAD   64
#define HID    768
#define SEQ    2048
#define BATCH  2
#define BH     (BATCH*N_HEAD)   // 24
#define MROWS  (BATCH*SEQ)      // 4096
#define SC2    0.18033688011112042f   // 0.125 * log2(e), folded into Q at gemm epilogue

static __device__ __forceinline__ f32x4 mfma32(bf16x8 a, bf16x8 b, f32x4 c) {
    return __builtin_amdgcn_mfma_f32_16x16x32_bf16(a, b, c, 0, 0, 0);
}

#define GLOAD_LDS16(gp, lp) __builtin_amdgcn_global_load_lds( \
    (const __attribute__((address_space(1))) void*)(gp), \
    (__attribute__((address_space(3))) void*)(lp), 16, 0, 0)

// ---------------- cast x (fp32 -> bf16), 8 elems/thread ----------------
__global__ __launch_bounds__(256) void cast_f32_bf16(const float* __restrict__ in,
                                                     __bf16* __restrict__ out, int n8) {
    int i = blockIdx.x * 256 + threadIdx.x;
    if (i >= n8) return;
    const float4* p = (const float4*)in;
    float4 a = p[2*i], b = p[2*i+1];
    bf16x8 o;
    o[0]=(__bf16)a.x; o[1]=(__bf16)a.y; o[2]=(__bf16)a.z; o[3]=(__bf16)a.w;
    o[4]=(__bf16)b.x; o[5]=(__bf16)b.y; o[6]=(__bf16)b.z; o[7]=(__bf16)b.w;
    *(bf16x8*)&out[(size_t)8*i] = o;
}

// ------------- transpose + cast: in[R][C] fp32 -> out[C][R] bf16 -------------
__global__ __launch_bounds__(256) void transpose_cast(const float* __restrict__ in,
                                                      __bf16* __restrict__ out, int R, int C) {
    __shared__ float t[32][33];
    int bx = blockIdx.x * 32;
    int by = blockIdx.y * 32;
    int x = threadIdx.x, y = threadIdx.y;  // (32, 8)
    #pragma unroll
    for (int i = 0; i < 32; i += 8) t[y+i][x] = in[(size_t)(by+y+i)*C + bx + x];
    __syncthreads();
    #pragma unroll
    for (int i = 0; i < 32; i += 8) out[(size_t)(bx+y+i)*R + by + x] = (__bf16)t[x][y+i];
}

// ---------------- MFMA GEMM, A[M][K] bf16, Bt[N][K] bf16 ----------------
template<int EPI>
__global__ __launch_bounds__(256) void gemm_bt(
    const __bf16* __restrict__ A, const __bf16* __restrict__ Bt,
    const float* __restrict__ bias, float* __restrict__ Cout,
    __bf16* __restrict__ Qo, __bf16* __restrict__ Ko, __bf16* __restrict__ Vo,
    int M, int N, int K)
{
    __shared__ __align__(16) __bf16 As[128*64];
    __shared__ __align__(16) __bf16 Bs[128*64];
    int tid = threadIdx.x;
    int m0 = blockIdx.y * 128, n0 = blockIdx.x * 128;
    int wave = tid >> 6, lane = tid & 63, lr = lane & 15, lk = lane >> 4;
    int wr = wave >> 1, wc = wave & 1;

    f32x4 acc[4][4];
    f32x4 zz = {0.f, 0.f, 0.f, 0.f};
    #pragma unroll
    for (int m = 0; m < 4; m++)
        #pragma unroll
        for (int n = 0; n < 4; n++) acc[m][n] = zz;

    for (int k0 = 0; k0 < K; k0 += 64) {
        #pragma unroll
        for (int i = 0; i < 4; i++) {
            int u = tid + 256*i;
            int row = u >> 3;
            int c = (u & 7) ^ (row & 7);
            GLOAD_LDS16(&A [(size_t)(m0+row)*K + k0 + c*8], &As[(size_t)u*8]);
            GLOAD_LDS16(&Bt[(size_t)(n0+row)*K + k0 + c*8], &Bs[(size_t)u*8]);
        }
        __syncthreads();
        #pragma unroll
        for (int kk = 0; kk < 2; kk++) {
            bf16x8 af[4], bfr[4];
            #pragma unroll
            for (int m = 0; m < 4; m++) {
                int row = wr*64 + m*16 + lr;
                int byte = (row*128 + kk*64 + lk*16) ^ ((row & 7) << 4);
                af[m] = *(const bf16x8*)((const char*)As + byte);
            }
            #pragma unroll
            for (int n = 0; n < 4; n++) {
                int row = wc*64 + n*16 + lr;
                int byte = (row*128 + kk*64 + lk*16) ^ ((row & 7) << 4);
                bfr[n] = *(const bf16x8*)((const char*)Bs + byte);
            }
            #pragma unroll
            for (int m = 0; m < 4; m++)
                #pragma unroll
                for (int n = 0; n < 4; n++)
                    acc[m][n] = mfma32(af[m], bfr[n], acc[m][n]);
        }
        __syncthreads();
    }

    #pragma unroll
    for (int m = 0; m < 4; m++)
    #pragma unroll
    for (int n = 0; n < 4; n++)
    #pragma unroll
    for (int r = 0; r < 4; r++) {
        int row = m0 + wr*64 + m*16 + lk*4 + r;
        int col = n0 + wc*64 + n*16 + lr;
        float v = acc[m][n][r] + bias[col];
        if (EPI == 0) {
            Cout[(size_t)row * N + col] = v;
        } else {
            int b_idx = row >> 11, s = row & 2047;
            int which = col / HID, hc = col % HID;
            int bh = b_idx * N_HEAD + (hc >> 6);
            int d = hc & 63;
            if (which == 0)      Qo[((size_t)bh*SEQ + s)*HEAD + d] = (__bf16)(v * SC2);
            else if (which == 1) Ko[((size_t)bh*SEQ + s)*HEAD + d] = (__bf16)v;
            else                 Vo[((size_t)bh*HEAD + d)*SEQ + s] = (__bf16)v;
        }
    }
}

// ---------------- causal flash attention ----------------
// 4 waves/block, KV tiles split mod 4 across waves; 32 q-rows/block.
// Swapped QK^T, static-max softmax (zero per-tile shuffles), K=32 PV with
// permuted-k concat, V prefetched into registers before QK (ILP).
// All register arrays statically indexed (rule #20).
__global__ __launch_bounds__(256, 3) void flash_attn(
    const __bf16* __restrict__ Q, const __bf16* __restrict__ Km,
    const __bf16* __restrict__ Vt, __bf16* __restrict__ ctx)
{
    __shared__ float xch[2][64][36];
    int tid = threadIdx.x;
    int w = tid >> 6;            // kv residue (mod 4) this wave owns
    int lane = tid & 63;
    int lr = lane & 15, lk = lane >> 4;
    int gid = blockIdx.x;
    int bh = gid % BH;
    int qi = 63 - gid / BH;      // longest first
    int b_idx = bh / N_HEAD, h = bh % N_HEAD;
    int q0 = qi * 32;
    const size_t hb = (size_t)bh * SEQ * HEAD;
    const size_t vb = (size_t)bh * HEAD * SEQ;
    f32x4 zz = {0.f, 0.f, 0.f, 0.f};

    bf16x8 qf0[2], qf1[2];
    #pragma unroll
    for (int kb = 0; kb < 2; kb++) {
        qf0[kb] = *(const bf16x8*)&Q[hb + (size_t)(q0 + lr)*HEAD + kb*32 + lk*8];
        qf1[kb] = *(const bf16x8*)&Q[hb + (size_t)(q0 + 16 + lr)*HEAD + kb*32 + lk*8];
    }

    f32x4 acc0[4], acc1[4];
    float ls0 = 0.f, ls1 = 0.f;
    #pragma unroll
    for (int db = 0; db < 4; db++) { acc0[db] = zz; acc1[db] = zz; }

    int nt = (q0 + 95) >> 6;     // ceil((q0+32)/64)

    bf16x8 kf[4][2];
    {
        int kv0 = w * 64;        // safe even when wave has no tiles (kv0 <= 192)
        #pragma unroll
        for (int cb = 0; cb < 4; cb++)
            #pragma unroll
            for (int kb = 0; kb < 2; kb++)
                kf[cb][kb] = *(const bf16x8*)&Km[hb + (size_t)(kv0 + cb*16 + lr)*HEAD + kb*32 + lk*8];
    }

    for (int t = w; t < nt; t += 4) {
        int kv0 = t * 64;

        // V prefetch into registers (latency hides under QK + softmax)
        bf16x8 v01[4], v23[4];
        #pragma unroll
        for (int db = 0; db < 4; db++) {
            const __bf16* vrow = &Vt[vb + (size_t)(db*16 + lr)*SEQ + kv0];
            bf16x4 a0 = *(const bf16x4*)&vrow[lk*4];
            bf16x4 a1 = *(const bf16x4*)&vrow[16 + lk*4];
            bf16x4 a2 = *(const bf16x4*)&vrow[32 + lk*4];
            bf16x4 a3 = *(const bf16x4*)&vrow[48 + lk*4];
            v01[db] = __builtin_shufflevector(a0, a1, 0,1,2,3,4,5,6,7);
            v23[db] = __builtin_shufflevector(a2, a3, 0,1,2,3,4,5,6,7);
        }

        // swapped QK^T: scR[cb][r] = S2[q=q0+R*16+lr][k=kv0+cb*16+lk*4+r]
        f32x4 sc0[4], sc1[4];
        __builtin_amdgcn_s_setprio(1);
        #pragma unroll
        for (int cb = 0; cb < 4; cb++) {
            f32x4 z0 = mfma32(kf[cb][0], qf0[0], zz);
            sc0[cb] = mfma32(kf[cb][1], qf0[1], z0);
            f32x4 z1 = mfma32(kf[cb][0], qf1[0], zz);
            sc1[cb] = mfma32(kf[cb][1], qf1[1], z1);
        }
        __builtin_amdgcn_s_setprio(0);

        // prefetch this wave's next K tile
        if (t + 4 < nt) {
            int kv1 = (t + 4) * 64;
            #pragma unroll
            for (int cb = 0; cb < 4; cb++)
                #pragma unroll
                for (int kb = 0; kb < 2; kb++)
                    kf[cb][kb] = *(const bf16x8*)&Km[hb + (size_t)(kv1 + cb*16 + lr)*HEAD + kb*32 + lk*8];
        }

        // causal mask on diagonal-touching tiles only
        if (kv0 + 63 > q0) {
            #pragma unroll
            for (int cb = 0; cb < 4; cb++)
                #pragma unroll
                for (int r = 0; r < 4; r++) {
                    int kg = kv0 + cb*16 + lk*4 + r;
                    if (kg > q0 + lr)      sc0[cb][r] = -30000.f;
                    if (kg > q0 + 16 + lr) sc1[cb][r] = -30000.f;
                }
        }

        // static-max softmax: P = exp2(sc); per-lane partial row-sums
        bf16x8 pa0[2], pa1[2];
        {
            float rs0 = 0.f, rs1 = 0.f;
            #pragma unroll
            for (int cb = 0; cb < 4; cb++)
                #pragma unroll
                for (int r = 0; r < 4; r++) {
                    float p0 = exp2f(sc0[cb][r]);
                    float p1 = exp2f(sc1[cb][r]);
                    rs0 += p0; rs1 += p1;
                    pa0[cb >> 1][(cb & 1)*4 + r] = (__bf16)p0;
                    pa1[cb >> 1][(cb & 1)*4 + r] = (__bf16)p1;
                }
            ls0 += rs0; ls1 += rs1;
        }

        // PV: K=32 MFMA with the same k-permutation on P and V
        __builtin_amdgcn_s_setprio(1);
        #pragma unroll
        for (int db = 0; db < 4; db++) {
            acc0[db] = mfma32(pa0[0], v01[db], acc0[db]);
            acc0[db] = mfma32(pa0[1], v23[db], acc0[db]);
            acc1[db] = mfma32(pa1[0], v01[db], acc1[db]);
            acc1[db] = mfma32(pa1[1], v23[db], acc1[db]);
        }
        __builtin_amdgcn_s_setprio(0);
    }

    // ---- combine stage 1: waves 2,3 fold into waves 0,1 ----
    if (w >= 2) {
        #pragma unroll
        for (int db = 0; db < 4; db++) {
            *(f32x4*)&xch[w-2][lane][db*4]      = acc0[db];
            *(f32x4*)&xch[w-2][lane][16 + db*4] = acc1[db];
        }
        xch[w-2][lane][32] = ls0;
        xch[w-2][lane][33] = ls1;
    }
    __syncthreads();
    if (w < 2) {
        #pragma unroll
        for (int db = 0; db < 4; db++) {
            acc0[db] += *(const f32x4*)&xch[w][lane][db*4];
            acc1[db] += *(const f32x4*)&xch[w][lane][16 + db*4];
        }
        ls0 += xch[w][lane][32];
        ls1 += xch[w][lane][33];
    }
    __syncthreads();
    // ---- combine stage 2: wave 0 keeps rb0, wave 1 keeps rb1 ----
    if (w == 0) {
        #pragma unroll
        for (int db = 0; db < 4; db++) *(f32x4*)&xch[0][lane][db*4] = acc1[db];
        xch[0][lane][16] = ls1;
    } else if (w == 1) {
        #pragma unroll
        for (int db = 0; db < 4; db++) *(f32x4*)&xch[1][lane][db*4] = acc0[db];
        xch[1][lane][16] = ls0;
    }
    __syncthreads();
    if (w >= 2) return;

    f32x4 accF[4];
    float lsF;
    if (w == 0) {
        #pragma unroll
        for (int db = 0; db < 4; db++) accF[db] = acc0[db] + *(const f32x4*)&xch[1][lane][db*4];
        lsF = ls0 + xch[1][lane][16];
    } else {
        #pragma unroll
        for (int db = 0; db < 4; db++) accF[db] = acc1[db] + *(const f32x4*)&xch[0][lane][db*4];
        lsF = ls1 + xch[0][lane][16];
    }

    float rs = lsF;
    rs += __shfl_xor(rs, 16);
    rs += __shfl_xor(rs, 32);
    float rl = 1.0f / rs;
    float li[4];
    #pragma unroll
    for (int r = 0; r < 4; r++)
        li[r] = __shfl(rl, (lane & 48) | (lk*4 + r));

    #pragma unroll
    for (int db = 0; db < 4; db++)
        #pragma unroll
        for (int r = 0; r < 4; r++) {
            int qg = q0 + w*16 + lk*4 + r;
            int d = db*16 + lr;
            ctx[((size_t)(b_idx*SEQ + qg))*HID + h*HEAD + d] = (__bf16)(accF[db][r] * li[r]);
        }
}

// ---------------- launch ----------------
extern "C" void kernel_launch(void* const* d_in, const int* in_sizes, int n_in,
                              void* d_out, int out_size, void* d_ws, size_t ws_size,
                              hipStream_t stream) {
    const float* x  = (const float*)d_in[0];   // [2,2048,768]
    const float* w1 = (const float*)d_in[1];   // [768,2304]
    const float* b1 = (const float*)d_in[2];   // [2304]
    const float* w2 = (const float*)d_in[3];   // [768,768]
    const float* b2 = (const float*)d_in[4];   // [768]
    float* out = (float*)d_out;

    char* ws = (char*)d_ws;
    size_t o = 0;
    __bf16* Xb  = (__bf16*)(ws + o); o += (size_t)MROWS*HID*2;
    __bf16* W1t = (__bf16*)(ws + o); o += (size_t)3*HID*HID*2;
    __bf16* W2t = (__bf16*)(ws + o); o += (size_t)HID*HID*2;
    __bf16* Qb  = (__bf16*)(ws + o); o += (size_t)MROWS*HID*2;
    __bf16* Kb  = (__bf16*)(ws + o); o += (size_t)MROWS*HID*2;
    __bf16* Vt  = (__bf16*)(ws + o); o += (size_t)MROWS*HID*2;
    __bf16* CTX = (__bf16*)(ws + o); o += (size_t)MROWS*HID*2;

    cast_f32_bf16<<<(MROWS*HID/8 + 255)/256, 256, 0, stream>>>(x, Xb, MROWS*HID/8);
    transpose_cast<<<dim3(3*HID/32, HID/32), dim3(32, 8), 0, stream>>>(w1, W1t, HID, 3*HID);
    transpose_cast<<<dim3(HID/32,   HID/32), dim3(32, 8), 0, stream>>>(w2, W2t, HID, HID);

    gemm_bt<1><<<dim3(3*HID/128, MROWS/128), 256, 0, stream>>>(
        Xb, W1t, b1, nullptr, Qb, Kb, Vt, MROWS, 3*HID, HID);

    flash_attn<<<dim3(64*BH), 256, 0, stream>>>(Qb, Kb, Vt, CTX);

    gemm_bt<0><<<dim3(HID/128, MROWS/128), 256, 0, stream>>>(
        CTX, W2t, b2, out, nullptr, nullptr, nullptr, MROWS, HID, HID);
}

// Round 7
// 198.501 us; speedup vs baseline: 1.1163x; 1.1163x over previous
//
#include <hip/hip_runtime.h>

typedef __bf16 bf16x8 __attribute__((ext_vector_type(8)));
typedef __bf16 bf16x4 __attribute__((ext_vector_type(4)));
typedef float  f32x4  __attribute__((ext_vector_type(4)));

#define N_HEAD 12
#define HEAD   64
#define HID    768
#define SEQ    2048
#define BATCH  2
#define BH     (BATCH*N_HEAD)   // 24
#define MROWS  (BATCH*SEQ)      // 4096
#define VSTR   2080             // padded V^T row stride: 4160B breaks 4KB set/channel aliasing
#define SC2    0.18033688011112042f   // 0.125 * log2(e), folded into Q at gemm epilogue

static __device__ __forceinline__ f32x4 mfma32(bf16x8 a, bf16x8 b, f32x4 c) {
    return __builtin_amdgcn_mfma_f32_16x16x32_bf16(a, b, c, 0, 0, 0);
}

#define GLOAD_LDS16(gp, lp) __builtin_amdgcn_global_load_lds( \
    (const __attribute__((address_space(1))) void*)(gp), \
    (__attribute__((address_space(3))) void*)(lp), 16, 0, 0)

// ---------------- cast x (fp32 -> bf16), 8 elems/thread ----------------
__global__ __launch_bounds__(256) void cast_f32_bf16(const float* __restrict__ in,
                                                     __bf16* __restrict__ out, int n8) {
    int i = blockIdx.x * 256 + threadIdx.x;
    if (i >= n8) return;
    const float4* p = (const float4*)in;
    float4 a = p[2*i], b = p[2*i+1];
    bf16x8 o;
    o[0]=(__bf16)a.x; o[1]=(__bf16)a.y; o[2]=(__bf16)a.z; o[3]=(__bf16)a.w;
    o[4]=(__bf16)b.x; o[5]=(__bf16)b.y; o[6]=(__bf16)b.z; o[7]=(__bf16)b.w;
    *(bf16x8*)&out[(size_t)8*i] = o;
}

// ------------- transpose + cast: in[R][C] fp32 -> out[C][R] bf16 -------------
__global__ __launch_bounds__(256) void transpose_cast(const float* __restrict__ in,
                                                      __bf16* __restrict__ out, int R, int C) {
    __shared__ float t[32][33];
    int bx = blockIdx.x * 32;
    int by = blockIdx.y * 32;
    int x = threadIdx.x, y = threadIdx.y;  // (32, 8)
    #pragma unroll
    for (int i = 0; i < 32; i += 8) t[y+i][x] = in[(size_t)(by+y+i)*C + bx + x];
    __syncthreads();
    #pragma unroll
    for (int i = 0; i < 32; i += 8) out[(size_t)(bx+y+i)*R + by + x] = (__bf16)t[x][y+i];
}

// ---------------- MFMA GEMM, A[M][K] bf16, Bt[N][K] bf16 ----------------
template<int EPI>
__global__ __launch_bounds__(256) void gemm_bt(
    const __bf16* __restrict__ A, const __bf16* __restrict__ Bt,
    const float* __restrict__ bias, float* __restrict__ Cout,
    __bf16* __restrict__ Qo, __bf16* __restrict__ Ko, __bf16* __restrict__ Vo,
    int M, int N, int K)
{
    __shared__ __align__(16) __bf16 As[128*64];
    __shared__ __align__(16) __bf16 Bs[128*64];
    int tid = threadIdx.x;
    int m0 = blockIdx.y * 128, n0 = blockIdx.x * 128;
    int wave = tid >> 6, lane = tid & 63, lr = lane & 15, lk = lane >> 4;
    int wr = wave >> 1, wc = wave & 1;

    f32x4 acc[4][4];
    f32x4 zz = {0.f, 0.f, 0.f, 0.f};
    #pragma unroll
    for (int m = 0; m < 4; m++)
        #pragma unroll
        for (int n = 0; n < 4; n++) acc[m][n] = zz;

    for (int k0 = 0; k0 < K; k0 += 64) {
        #pragma unroll
        for (int i = 0; i < 4; i++) {
            int u = tid + 256*i;
            int row = u >> 3;
            int c = (u & 7) ^ (row & 7);
            GLOAD_LDS16(&A [(size_t)(m0+row)*K + k0 + c*8], &As[(size_t)u*8]);
            GLOAD_LDS16(&Bt[(size_t)(n0+row)*K + k0 + c*8], &Bs[(size_t)u*8]);
        }
        __syncthreads();
        #pragma unroll
        for (int kk = 0; kk < 2; kk++) {
            bf16x8 af[4], bfr[4];
            #pragma unroll
            for (int m = 0; m < 4; m++) {
                int row = wr*64 + m*16 + lr;
                int byte = (row*128 + kk*64 + lk*16) ^ ((row & 7) << 4);
                af[m] = *(const bf16x8*)((const char*)As + byte);
            }
            #pragma unroll
            for (int n = 0; n < 4; n++) {
                int row = wc*64 + n*16 + lr;
                int byte = (row*128 + kk*64 + lk*16) ^ ((row & 7) << 4);
                bfr[n] = *(const bf16x8*)((const char*)Bs + byte);
            }
            #pragma unroll
            for (int m = 0; m < 4; m++)
                #pragma unroll
                for (int n = 0; n < 4; n++)
                    acc[m][n] = mfma32(af[m], bfr[n], acc[m][n]);
        }
        __syncthreads();
    }

    #pragma unroll
    for (int m = 0; m < 4; m++)
    #pragma unroll
    for (int n = 0; n < 4; n++)
    #pragma unroll
    for (int r = 0; r < 4; r++) {
        int row = m0 + wr*64 + m*16 + lk*4 + r;
        int col = n0 + wc*64 + n*16 + lr;
        float v = acc[m][n][r] + bias[col];
        if (EPI == 0) {
            Cout[(size_t)row * N + col] = v;
        } else {
            int b_idx = row >> 11, s = row & 2047;
            int which = col / HID, hc = col % HID;
            int bh = b_idx * N_HEAD + (hc >> 6);
            int d = hc & 63;
            if (which == 0)      Qo[((size_t)bh*SEQ + s)*HEAD + d] = (__bf16)(v * SC2);
            else if (which == 1) Ko[((size_t)bh*SEQ + s)*HEAD + d] = (__bf16)v;
            else                 Vo[((size_t)bh*HEAD + d)*VSTR + s] = (__bf16)v;
        }
    }
}

// ---------------- causal flash attention ----------------
// 4 waves/block, KV tiles split mod 4 across waves; 32 q-rows/block.
// Swapped QK^T, static-max softmax (zero per-tile shuffles), K=32 PV with
// permuted-k concat, V prefetched into registers before QK (ILP).
// All register arrays statically indexed (rule #20). V^T rows padded (VSTR).
__global__ __launch_bounds__(256, 3) void flash_attn(
    const __bf16* __restrict__ Q, const __bf16* __restrict__ Km,
    const __bf16* __restrict__ Vt, __bf16* __restrict__ ctx)
{
    __shared__ float xch[2][64][36];
    int tid = threadIdx.x;
    int w = tid >> 6;            // kv residue (mod 4) this wave owns
    int lane = tid & 63;
    int lr = lane & 15, lk = lane >> 4;
    int gid = blockIdx.x;
    int bh = gid % BH;
    int qi = 63 - gid / BH;      // longest first
    int b_idx = bh / N_HEAD, h = bh % N_HEAD;
    int q0 = qi * 32;
    const size_t hb = (size_t)bh * SEQ * HEAD;
    const size_t vb = (size_t)bh * HEAD * VSTR;
    f32x4 zz = {0.f, 0.f, 0.f, 0.f};

    bf16x8 qf0[2], qf1[2];
    #pragma unroll
    for (int kb = 0; kb < 2; kb++) {
        qf0[kb] = *(const bf16x8*)&Q[hb + (size_t)(q0 + lr)*HEAD + kb*32 + lk*8];
        qf1[kb] = *(const bf16x8*)&Q[hb + (size_t)(q0 + 16 + lr)*HEAD + kb*32 + lk*8];
    }

    f32x4 acc0[4], acc1[4];
    float ls0 = 0.f, ls1 = 0.f;
    #pragma unroll
    for (int db = 0; db < 4; db++) { acc0[db] = zz; acc1[db] = zz; }

    int nt = (q0 + 95) >> 6;     // ceil((q0+32)/64)

    bf16x8 kf[4][2];
    {
        int kv0 = w * 64;        // safe even when wave has no tiles (kv0 <= 192)
        #pragma unroll
        for (int cb = 0; cb < 4; cb++)
            #pragma unroll
            for (int kb = 0; kb < 2; kb++)
                kf[cb][kb] = *(const bf16x8*)&Km[hb + (size_t)(kv0 + cb*16 + lr)*HEAD + kb*32 + lk*8];
    }

    for (int t = w; t < nt; t += 4) {
        int kv0 = t * 64;

        // V prefetch into registers (latency hides under QK + softmax)
        bf16x8 v01[4], v23[4];
        #pragma unroll
        for (int db = 0; db < 4; db++) {
            const __bf16* vrow = &Vt[vb + (size_t)(db*16 + lr)*VSTR + kv0];
            bf16x4 a0 = *(const bf16x4*)&vrow[lk*4];
            bf16x4 a1 = *(const bf16x4*)&vrow[16 + lk*4];
            bf16x4 a2 = *(const bf16x4*)&vrow[32 + lk*4];
            bf16x4 a3 = *(const bf16x4*)&vrow[48 + lk*4];
            v01[db] = __builtin_shufflevector(a0, a1, 0,1,2,3,4,5,6,7);
            v23[db] = __builtin_shufflevector(a2, a3, 0,1,2,3,4,5,6,7);
        }

        // swapped QK^T: scR[cb][r] = S2[q=q0+R*16+lr][k=kv0+cb*16+lk*4+r]
        f32x4 sc0[4], sc1[4];
        __builtin_amdgcn_s_setprio(1);
        #pragma unroll
        for (int cb = 0; cb < 4; cb++) {
            f32x4 z0 = mfma32(kf[cb][0], qf0[0], zz);
            sc0[cb] = mfma32(kf[cb][1], qf0[1], z0);
            f32x4 z1 = mfma32(kf[cb][0], qf1[0], zz);
            sc1[cb] = mfma32(kf[cb][1], qf1[1], z1);
        }
        __builtin_amdgcn_s_setprio(0);

        // prefetch this wave's next K tile
        if (t + 4 < nt) {
            int kv1 = (t + 4) * 64;
            #pragma unroll
            for (int cb = 0; cb < 4; cb++)
                #pragma unroll
                for (int kb = 0; kb < 2; kb++)
                    kf[cb][kb] = *(const bf16x8*)&Km[hb + (size_t)(kv1 + cb*16 + lr)*HEAD + kb*32 + lk*8];
        }

        // causal mask on diagonal-touching tiles only
        if (kv0 + 63 > q0) {
            #pragma unroll
            for (int cb = 0; cb < 4; cb++)
                #pragma unroll
                for (int r = 0; r < 4; r++) {
                    int kg = kv0 + cb*16 + lk*4 + r;
                    if (kg > q0 + lr)      sc0[cb][r] = -30000.f;
                    if (kg > q0 + 16 + lr) sc1[cb][r] = -30000.f;
                }
        }

        // static-max softmax: P = exp2(sc); per-lane partial row-sums
        bf16x8 pa0[2], pa1[2];
        {
            float rs0 = 0.f, rs1 = 0.f;
            #pragma unroll
            for (int cb = 0; cb < 4; cb++)
                #pragma unroll
                for (int r = 0; r < 4; r++) {
                    float p0 = exp2f(sc0[cb][r]);
                    float p1 = exp2f(sc1[cb][r]);
                    rs0 += p0; rs1 += p1;
                    pa0[cb >> 1][(cb & 1)*4 + r] = (__bf16)p0;
                    pa1[cb >> 1][(cb & 1)*4 + r] = (__bf16)p1;
                }
            ls0 += rs0; ls1 += rs1;
        }

        // PV: K=32 MFMA with the same k-permutation on P and V
        __builtin_amdgcn_s_setprio(1);
        #pragma unroll
        for (int db = 0; db < 4; db++) {
            acc0[db] = mfma32(pa0[0], v01[db], acc0[db]);
            acc0[db] = mfma32(pa0[1], v23[db], acc0[db]);
            acc1[db] = mfma32(pa1[0], v01[db], acc1[db]);
            acc1[db] = mfma32(pa1[1], v23[db], acc1[db]);
        }
        __builtin_amdgcn_s_setprio(0);
    }

    // ---- combine stage 1: waves 2,3 fold into waves 0,1 ----
    if (w >= 2) {
        #pragma unroll
        for (int db = 0; db < 4; db++) {
            *(f32x4*)&xch[w-2][lane][db*4]      = acc0[db];
            *(f32x4*)&xch[w-2][lane][16 + db*4] = acc1[db];
        }
        xch[w-2][lane][32] = ls0;
        xch[w-2][lane][33] = ls1;
    }
    __syncthreads();
    if (w < 2) {
        #pragma unroll
        for (int db = 0; db < 4; db++) {
            acc0[db] += *(const f32x4*)&xch[w][lane][db*4];
            acc1[db] += *(const f32x4*)&xch[w][lane][16 + db*4];
        }
        ls0 += xch[w][lane][32];
        ls1 += xch[w][lane][33];
    }
    __syncthreads();
    // ---- combine stage 2: wave 0 keeps rb0, wave 1 keeps rb1 ----
    if (w == 0) {
        #pragma unroll
        for (int db = 0; db < 4; db++) *(f32x4*)&xch[0][lane][db*4] = acc1[db];
        xch[0][lane][16] = ls1;
    } else if (w == 1) {
        #pragma unroll
        for (int db = 0; db < 4; db++) *(f32x4*)&xch[1][lane][db*4] = acc0[db];
        xch[1][lane][16] = ls0;
    }
    __syncthreads();
    if (w >= 2) return;

    f32x4 accF[4];
    float lsF;
    if (w == 0) {
        #pragma unroll
        for (int db = 0; db < 4; db++) accF[db] = acc0[db] + *(const f32x4*)&xch[1][lane][db*4];
        lsF = ls0 + xch[1][lane][16];
    } else {
        #pragma unroll
        for (int db = 0; db < 4; db++) accF[db] = acc1[db] + *(const f32x4*)&xch[0][lane][db*4];
        lsF = ls1 + xch[0][lane][16];
    }

    float rs = lsF;
    rs += __shfl_xor(rs, 16);
    rs += __shfl_xor(rs, 32);
    float rl = 1.0f / rs;
    float li[4];
    #pragma unroll
    for (int r = 0; r < 4; r++)
        li[r] = __shfl(rl, (lane & 48) | (lk*4 + r));

    #pragma unroll
    for (int db = 0; db < 4; db++)
        #pragma unroll
        for (int r = 0; r < 4; r++) {
            int qg = q0 + w*16 + lk*4 + r;
            int d = db*16 + lr;
            ctx[((size_t)(b_idx*SEQ + qg))*HID + h*HEAD + d] = (__bf16)(accF[db][r] * li[r]);
        }
}

// ---------------- launch ----------------
extern "C" void kernel_launch(void* const* d_in, const int* in_sizes, int n_in,
                              void* d_out, int out_size, void* d_ws, size_t ws_size,
                              hipStream_t stream) {
    const float* x  = (const float*)d_in[0];   // [2,2048,768]
    const float* w1 = (const float*)d_in[1];   // [768,2304]
    const float* b1 = (const float*)d_in[2];   // [2304]
    const float* w2 = (const float*)d_in[3];   // [768,768]
    const float* b2 = (const float*)d_in[4];   // [768]
    float* out = (float*)d_out;

    char* ws = (char*)d_ws;
    size_t o = 0;
    __bf16* Xb  = (__bf16*)(ws + o); o += (size_t)MROWS*HID*2;
    __bf16* W1t = (__bf16*)(ws + o); o += (size_t)3*HID*HID*2;
    __bf16* W2t = (__bf16*)(ws + o); o += (size_t)HID*HID*2;
    __bf16* Qb  = (__bf16*)(ws + o); o += (size_t)MROWS*HID*2;
    __bf16* Kb  = (__bf16*)(ws + o); o += (size_t)MROWS*HID*2;
    __bf16* Vt  = (__bf16*)(ws + o); o += (size_t)BH*HEAD*VSTR*2;
    __bf16* CTX = (__bf16*)(ws + o); o += (size_t)MROWS*HID*2;

    cast_f32_bf16<<<(MROWS*HID/8 + 255)/256, 256, 0, stream>>>(x, Xb, MROWS*HID/8);
    transpose_cast<<<dim3(3*HID/32, HID/32), dim3(32, 8), 0, stream>>>(w1, W1t, HID, 3*HID);
    transpose_cast<<<dim3(HID/32,   HID/32), dim3(32, 8), 0, stream>>>(w2, W2t, HID, HID);

    gemm_bt<1><<<dim3(3*HID/128, MROWS/128), 256, 0, stream>>>(
        Xb, W1t, b1, nullptr, Qb, Kb, Vt, MROWS, 3*HID, HID);

    flash_attn<<<dim3(64*BH), 256, 0, stream>>>(Qb, Kb, Vt, CTX);

    gemm_bt<0><<<dim3(HID/128, MROWS/128), 256, 0, stream>>>(
        CTX, W2t, b2, out, nullptr, nullptr, nullptr, MROWS, HID, HID);
}

// Round 8
// 189.196 us; speedup vs baseline: 1.1712x; 1.0492x over previous
//
#include <hip/hip_runtime.h>

typedef __bf16 bf16x8 __attribute__((ext_vector_type(8)));
typedef __bf16 bf16x4 __attribute__((ext_vector_type(4)));
typedef float  f32x4  __attribute__((ext_vector_type(4)));

#define N_HEAD 12
#define HEAD   64
#define HID    768
#define SEQ    2048
#define BATCH  2
#define BH     (BATCH*N_HEAD)   // 24
#define MROWS  (BATCH*SEQ)      // 4096
#define VSTR   2080             // padded V^T row stride (breaks 4KB aliasing)
#define SC2    0.18033688011112042f   // 0.125 * log2(e), folded into Q at gemm epilogue

static __device__ __forceinline__ f32x4 mfma32(bf16x8 a, bf16x8 b, f32x4 c) {
    return __builtin_amdgcn_mfma_f32_16x16x32_bf16(a, b, c, 0, 0, 0);
}

#define GLOAD_LDS16(gp, lp) __builtin_amdgcn_global_load_lds( \
    (const __attribute__((address_space(1))) void*)(gp), \
    (__attribute__((address_space(3))) void*)(lp), 16, 0, 0)

// ---------------- cast x (fp32 -> bf16), 8 elems/thread ----------------
__global__ __launch_bounds__(256) void cast_f32_bf16(const float* __restrict__ in,
                                                     __bf16* __restrict__ out, int n8) {
    int i = blockIdx.x * 256 + threadIdx.x;
    if (i >= n8) return;
    const float4* p = (const float4*)in;
    float4 a = p[2*i], b = p[2*i+1];
    bf16x8 o;
    o[0]=(__bf16)a.x; o[1]=(__bf16)a.y; o[2]=(__bf16)a.z; o[3]=(__bf16)a.w;
    o[4]=(__bf16)b.x; o[5]=(__bf16)b.y; o[6]=(__bf16)b.z; o[7]=(__bf16)b.w;
    *(bf16x8*)&out[(size_t)8*i] = o;
}

// ------------- transpose + cast: in[R][C] fp32 -> out[C][R] bf16 -------------
__global__ __launch_bounds__(256) void transpose_cast(const float* __restrict__ in,
                                                      __bf16* __restrict__ out, int R, int C) {
    __shared__ float t[32][33];
    int bx = blockIdx.x * 32;
    int by = blockIdx.y * 32;
    int x = threadIdx.x, y = threadIdx.y;  // (32, 8)
    #pragma unroll
    for (int i = 0; i < 32; i += 8) t[y+i][x] = in[(size_t)(by+y+i)*C + bx + x];
    __syncthreads();
    #pragma unroll
    for (int i = 0; i < 32; i += 8) out[(size_t)(bx+y+i)*R + by + x] = (__bf16)t[x][y+i];
}

// ---------------- MFMA GEMM, A[M][K] bf16, Bt[N][K] bf16 ----------------
template<int EPI>
__global__ __launch_bounds__(256) void gemm_bt(
    const __bf16* __restrict__ A, const __bf16* __restrict__ Bt,
    const float* __restrict__ bias, float* __restrict__ Cout,
    __bf16* __restrict__ Qo, __bf16* __restrict__ Ko, __bf16* __restrict__ Vo,
    int M, int N, int K)
{
    __shared__ __align__(16) __bf16 As[128*64];
    __shared__ __align__(16) __bf16 Bs[128*64];
    int tid = threadIdx.x;
    int m0 = blockIdx.y * 128, n0 = blockIdx.x * 128;
    int wave = tid >> 6, lane = tid & 63, lr = lane & 15, lk = lane >> 4;
    int wr = wave >> 1, wc = wave & 1;

    f32x4 acc[4][4];
    f32x4 zz = {0.f, 0.f, 0.f, 0.f};
    #pragma unroll
    for (int m = 0; m < 4; m++)
        #pragma unroll
        for (int n = 0; n < 4; n++) acc[m][n] = zz;

    for (int k0 = 0; k0 < K; k0 += 64) {
        #pragma unroll
        for (int i = 0; i < 4; i++) {
            int u = tid + 256*i;
            int row = u >> 3;
            int c = (u & 7) ^ (row & 7);
            GLOAD_LDS16(&A [(size_t)(m0+row)*K + k0 + c*8], &As[(size_t)u*8]);
            GLOAD_LDS16(&Bt[(size_t)(n0+row)*K + k0 + c*8], &Bs[(size_t)u*8]);
        }
        __syncthreads();
        #pragma unroll
        for (int kk = 0; kk < 2; kk++) {
            bf16x8 af[4], bfr[4];
            #pragma unroll
            for (int m = 0; m < 4; m++) {
                int row = wr*64 + m*16 + lr;
                int byte = (row*128 + kk*64 + lk*16) ^ ((row & 7) << 4);
                af[m] = *(const bf16x8*)((const char*)As + byte);
            }
            #pragma unroll
            for (int n = 0; n < 4; n++) {
                int row = wc*64 + n*16 + lr;
                int byte = (row*128 + kk*64 + lk*16) ^ ((row & 7) << 4);
                bfr[n] = *(const bf16x8*)((const char*)Bs + byte);
            }
            #pragma unroll
            for (int m = 0; m < 4; m++)
                #pragma unroll
                for (int n = 0; n < 4; n++)
                    acc[m][n] = mfma32(af[m], bfr[n], acc[m][n]);
        }
        __syncthreads();
    }

    #pragma unroll
    for (int m = 0; m < 4; m++)
    #pragma unroll
    for (int n = 0; n < 4; n++)
    #pragma unroll
    for (int r = 0; r < 4; r++) {
        int row = m0 + wr*64 + m*16 + lk*4 + r;
        int col = n0 + wc*64 + n*16 + lr;
        float v = acc[m][n][r] + bias[col];
        if (EPI == 0) {
            Cout[(size_t)row * N + col] = v;
        } else {
            int b_idx = row >> 11, s = row & 2047;
            int which = col / HID, hc = col % HID;
            int bh = b_idx * N_HEAD + (hc >> 6);
            int d = hc & 63;
            if (which == 0)      Qo[((size_t)bh*SEQ + s)*HEAD + d] = (__bf16)(v * SC2);
            else if (which == 1) Ko[((size_t)bh*SEQ + s)*HEAD + d] = (__bf16)v;
            else                 Vo[((size_t)bh*HEAD + d)*VSTR + s] = (__bf16)v;
        }
    }
}

// ---------------- causal flash attention (LDS-shared KV, 2-phase dbuf) ----------------
// Block: 128 q-rows (wave w owns rows qb*128+w*32..+31) x one bh. All 4 waves
// consume the SAME KV tile staged once per block into LDS (K[64s][64d] swizzled,
// V^T[64d][64k] swizzled). Swapped QK^T, static-max softmax, K=32 permuted PV.
__global__ __launch_bounds__(256, 2) void flash_attn(
    const __bf16* __restrict__ Q, const __bf16* __restrict__ Km,
    const __bf16* __restrict__ Vt, __bf16* __restrict__ ctx)
{
    __shared__ __align__(16) __bf16 Ks[2][64*64];
    __shared__ __align__(16) __bf16 Vs[2][64*64];
    int tid = threadIdx.x;
    int w = tid >> 6;            // q sub-block this wave owns
    int lane = tid & 63;
    int lr = lane & 15, lk = lane >> 4;
    int gid = blockIdx.x;
    int bh = gid % BH;
    int qb = 15 - gid / BH;      // longest first
    int b_idx = bh / N_HEAD, h = bh % N_HEAD;
    int q0 = qb*128 + w*32;
    const size_t hb = (size_t)bh * SEQ * HEAD;
    const size_t vbh = (size_t)bh * HEAD * VSTR;
    f32x4 zz = {0.f, 0.f, 0.f, 0.f};

    // staging geometry (per thread, 2 units each for K and V)
    int u0 = tid, u1 = tid + 256;
    int kr0 = u0 >> 3, kc0 = (u0 & 7) ^ (kr0 & 7);
    int kr1 = u1 >> 3, kc1 = (u1 & 7) ^ (kr1 & 7);

    bf16x8 qf0[2], qf1[2];
    #pragma unroll
    for (int kb = 0; kb < 2; kb++) {
        qf0[kb] = *(const bf16x8*)&Q[hb + (size_t)(q0 + lr)*HEAD + kb*32 + lk*8];
        qf1[kb] = *(const bf16x8*)&Q[hb + (size_t)(q0 + 16 + lr)*HEAD + kb*32 + lk*8];
    }

    f32x4 acc0[4], acc1[4];
    float ls0 = 0.f, ls1 = 0.f;
    #pragma unroll
    for (int db = 0; db < 4; db++) { acc0[db] = zz; acc1[db] = zz; }

    int nt = 2*qb + 2;

    // prologue: stage tile 0 into buf 0
    GLOAD_LDS16(&Km[hb + (size_t)kr0*HEAD + kc0*8],  &Ks[0][(size_t)u0*8]);
    GLOAD_LDS16(&Km[hb + (size_t)kr1*HEAD + kc1*8],  &Ks[0][(size_t)u1*8]);
    GLOAD_LDS16(&Vt[vbh + (size_t)kr0*VSTR + kc0*8], &Vs[0][(size_t)u0*8]);
    GLOAD_LDS16(&Vt[vbh + (size_t)kr1*VSTR + kc1*8], &Vs[0][(size_t)u1*8]);
    __syncthreads();

    for (int t = 0; t < nt; t++) {
        int kv0 = t * 64;
        int cur = t & 1;
        const char* kbuf = (const char*)&Ks[cur][0];
        const char* vbuf = (const char*)&Vs[cur][0];

        // stage next tile into other buffer (overlaps compute; drained by syncthreads)
        if (t + 1 < nt) {
            int kv1 = kv0 + 64;
            int nxt = cur ^ 1;
            GLOAD_LDS16(&Km[hb + (size_t)(kv1 + kr0)*HEAD + kc0*8],  &Ks[nxt][(size_t)u0*8]);
            GLOAD_LDS16(&Km[hb + (size_t)(kv1 + kr1)*HEAD + kc1*8],  &Ks[nxt][(size_t)u1*8]);
            GLOAD_LDS16(&Vt[vbh + (size_t)kr0*VSTR + kv1 + kc0*8],   &Vs[nxt][(size_t)u0*8]);
            GLOAD_LDS16(&Vt[vbh + (size_t)kr1*VSTR + kv1 + kc1*8],   &Vs[nxt][(size_t)u1*8]);
        }

        // K fragments from LDS (swizzled b128, conflict-free)
        bf16x8 kf[4][2];
        #pragma unroll
        for (int cb = 0; cb < 4; cb++)
            #pragma unroll
            for (int kb = 0; kb < 2; kb++) {
                int row = cb*16 + lr;
                int byte = (row*128 + kb*64 + lk*16) ^ ((row & 7) << 4);
                kf[cb][kb] = *(const bf16x8*)(kbuf + byte);
            }

        // V fragments from LDS (swizzled b64; concat with same k-permutation as P)
        bf16x8 v01[4], v23[4];
        #pragma unroll
        for (int db = 0; db < 4; db++) {
            int row = db*16 + lr;
            int rx = (row & 7) << 4;
            bf16x4 a0 = *(const bf16x4*)(vbuf + ((row*128 + lk*8)       ^ rx));
            bf16x4 a1 = *(const bf16x4*)(vbuf + ((row*128 + 32 + lk*8)  ^ rx));
            bf16x4 a2 = *(const bf16x4*)(vbuf + ((row*128 + 64 + lk*8)  ^ rx));
            bf16x4 a3 = *(const bf16x4*)(vbuf + ((row*128 + 96 + lk*8)  ^ rx));
            v01[db] = __builtin_shufflevector(a0, a1, 0,1,2,3,4,5,6,7);
            v23[db] = __builtin_shufflevector(a2, a3, 0,1,2,3,4,5,6,7);
        }

        // swapped QK^T
        f32x4 sc0[4], sc1[4];
        __builtin_amdgcn_s_setprio(1);
        #pragma unroll
        for (int cb = 0; cb < 4; cb++) {
            f32x4 z0 = mfma32(kf[cb][0], qf0[0], zz);
            sc0[cb] = mfma32(kf[cb][1], qf0[1], z0);
            f32x4 z1 = mfma32(kf[cb][0], qf1[0], zz);
            sc1[cb] = mfma32(kf[cb][1], qf1[1], z1);
        }
        __builtin_amdgcn_s_setprio(0);

        // causal mask on diagonal-touching tiles only (per-wave)
        if (kv0 + 63 > q0) {
            #pragma unroll
            for (int cb = 0; cb < 4; cb++)
                #pragma unroll
                for (int r = 0; r < 4; r++) {
                    int kg = kv0 + cb*16 + lk*4 + r;
                    if (kg > q0 + lr)      sc0[cb][r] = -30000.f;
                    if (kg > q0 + 16 + lr) sc1[cb][r] = -30000.f;
                }
        }

        // static-max softmax
        bf16x8 pa0[2], pa1[2];
        {
            float rs0 = 0.f, rs1 = 0.f;
            #pragma unroll
            for (int cb = 0; cb < 4; cb++)
                #pragma unroll
                for (int r = 0; r < 4; r++) {
                    float p0 = exp2f(sc0[cb][r]);
                    float p1 = exp2f(sc1[cb][r]);
                    rs0 += p0; rs1 += p1;
                    pa0[cb >> 1][(cb & 1)*4 + r] = (__bf16)p0;
                    pa1[cb >> 1][(cb & 1)*4 + r] = (__bf16)p1;
                }
            ls0 += rs0; ls1 += rs1;
        }

        // PV
        __builtin_amdgcn_s_setprio(1);
        #pragma unroll
        for (int db = 0; db < 4; db++) {
            acc0[db] = mfma32(pa0[0], v01[db], acc0[db]);
            acc0[db] = mfma32(pa0[1], v23[db], acc0[db]);
            acc1[db] = mfma32(pa1[0], v01[db], acc1[db]);
            acc1[db] = mfma32(pa1[1], v23[db], acc1[db]);
        }
        __builtin_amdgcn_s_setprio(0);

        __syncthreads();   // drains staging loads + LDS reads; next tile ready
    }

    // epilogue: each wave finalizes its own 32 rows
    float rs0 = ls0;
    rs0 += __shfl_xor(rs0, 16);
    rs0 += __shfl_xor(rs0, 32);
    float rs1 = ls1;
    rs1 += __shfl_xor(rs1, 16);
    rs1 += __shfl_xor(rs1, 32);
    float rl0 = 1.0f / rs0, rl1 = 1.0f / rs1;
    float li0[4], li1[4];
    #pragma unroll
    for (int r = 0; r < 4; r++) {
        li0[r] = __shfl(rl0, (lane & 48) | (lk*4 + r));
        li1[r] = __shfl(rl1, (lane & 48) | (lk*4 + r));
    }

    #pragma unroll
    for (int db = 0; db < 4; db++)
        #pragma unroll
        for (int r = 0; r < 4; r++) {
            int d = db*16 + lr;
            int qg0 = q0 + lk*4 + r;
            int qg1 = q0 + 16 + lk*4 + r;
            ctx[((size_t)(b_idx*SEQ + qg0))*HID + h*HEAD + d] = (__bf16)(acc0[db][r] * li0[r]);
            ctx[((size_t)(b_idx*SEQ + qg1))*HID + h*HEAD + d] = (__bf16)(acc1[db][r] * li1[r]);
        }
}

// ---------------- launch ----------------
extern "C" void kernel_launch(void* const* d_in, const int* in_sizes, int n_in,
                              void* d_out, int out_size, void* d_ws, size_t ws_size,
                              hipStream_t stream) {
    const float* x  = (const float*)d_in[0];   // [2,2048,768]
    const float* w1 = (const float*)d_in[1];   // [768,2304]
    const float* b1 = (const float*)d_in[2];   // [2304]
    const float* w2 = (const float*)d_in[3];   // [768,768]
    const float* b2 = (const float*)d_in[4];   // [768]
    float* out = (float*)d_out;

    char* ws = (char*)d_ws;
    size_t o = 0;
    __bf16* Xb  = (__bf16*)(ws + o); o += (size_t)MROWS*HID*2;
    __bf16* W1t = (__bf16*)(ws + o); o += (size_t)3*HID*HID*2;
    __bf16* W2t = (__bf16*)(ws + o); o += (size_t)HID*HID*2;
    __bf16* Qb  = (__bf16*)(ws + o); o += (size_t)MROWS*HID*2;
    __bf16* Kb  = (__bf16*)(ws + o); o += (size_t)MROWS*HID*2;
    __bf16* Vt  = (__bf16*)(ws + o); o += (size_t)BH*HEAD*VSTR*2;
    __bf16* CTX = (__bf16*)(ws + o); o += (size_t)MROWS*HID*2;

    cast_f32_bf16<<<(MROWS*HID/8 + 255)/256, 256, 0, stream>>>(x, Xb, MROWS*HID/8);
    transpose_cast<<<dim3(3*HID/32, HID/32), dim3(32, 8), 0, stream>>>(w1, W1t, HID, 3*HID);
    transpose_cast<<<dim3(HID/32,   HID/32), dim3(32, 8), 0, stream>>>(w2, W2t, HID, HID);

    gemm_bt<1><<<dim3(3*HID/128, MROWS/128), 256, 0, stream>>>(
        Xb, W1t, b1, nullptr, Qb, Kb, Vt, MROWS, 3*HID, HID);

    flash_attn<<<dim3(16*BH), 256, 0, stream>>>(Qb, Kb, Vt, CTX);

    gemm_bt<0><<<dim3(HID/128, MROWS/128), 256, 0, stream>>>(
        CTX, W2t, b2, out, nullptr, nullptr, nullptr, MROWS, HID, HID);
}

// Round 9
// 170.110 us; speedup vs baseline: 1.3026x; 1.1122x over previous
//
#include <hip/hip_runtime.h>

typedef __bf16 bf16x8 __attribute__((ext_vector_type(8)));
typedef __bf16 bf16x4 __attribute__((ext_vector_type(4)));
typedef float  f32x4  __attribute__((ext_vector_type(4)));

#define N_HEAD 12
#define HEAD   64
#define HID    768
#define SEQ    2048
#define BATCH  2
#define BH     (BATCH*N_HEAD)   // 24
#define MROWS  (BATCH*SEQ)      // 4096
#define VSTR   2080             // padded V^T row stride (breaks 4KB aliasing)
#define SC2    0.18033688011112042f   // 0.125 * log2(e), folded into Q at gemm epilogue

static __device__ __forceinline__ f32x4 mfma32(bf16x8 a, bf16x8 b, f32x4 c) {
    return __builtin_amdgcn_mfma_f32_16x16x32_bf16(a, b, c, 0, 0, 0);
}

#define GLOAD_LDS16(gp, lp) __builtin_amdgcn_global_load_lds( \
    (const __attribute__((address_space(1))) void*)(gp), \
    (__attribute__((address_space(3))) void*)(lp), 16, 0, 0)

// ---------------- cast x (fp32 -> bf16), 8 elems/thread ----------------
__global__ __launch_bounds__(256) void cast_f32_bf16(const float* __restrict__ in,
                                                     __bf16* __restrict__ out, int n8) {
    int i = blockIdx.x * 256 + threadIdx.x;
    if (i >= n8) return;
    const float4* p = (const float4*)in;
    float4 a = p[2*i], b = p[2*i+1];
    bf16x8 o;
    o[0]=(__bf16)a.x; o[1]=(__bf16)a.y; o[2]=(__bf16)a.z; o[3]=(__bf16)a.w;
    o[4]=(__bf16)b.x; o[5]=(__bf16)b.y; o[6]=(__bf16)b.z; o[7]=(__bf16)b.w;
    *(bf16x8*)&out[(size_t)8*i] = o;
}

// ------------- transpose + cast: in[R][C] fp32 -> out[C][R] bf16 -------------
__global__ __launch_bounds__(256) void transpose_cast(const float* __restrict__ in,
                                                      __bf16* __restrict__ out, int R, int C) {
    __shared__ float t[32][33];
    int bx = blockIdx.x * 32;
    int by = blockIdx.y * 32;
    int x = threadIdx.x, y = threadIdx.y;  // (32, 8)
    #pragma unroll
    for (int i = 0; i < 32; i += 8) t[y+i][x] = in[(size_t)(by+y+i)*C + bx + x];
    __syncthreads();
    #pragma unroll
    for (int i = 0; i < 32; i += 8) out[(size_t)(bx+y+i)*R + by + x] = (__bf16)t[x][y+i];
}

// ---------------- MFMA GEMM, A[M][K] bf16, Bt[N][K] bf16 ----------------
// 2-phase double-buffered staging: stage(k+1) issued before compute(k),
// one barrier per K-step (T3 minimum recipe).
template<int EPI>
__global__ __launch_bounds__(256) void gemm_bt(
    const __bf16* __restrict__ A, const __bf16* __restrict__ Bt,
    const float* __restrict__ bias, float* __restrict__ Cout,
    __bf16* __restrict__ Qo, __bf16* __restrict__ Ko, __bf16* __restrict__ Vo,
    int M, int N, int K)
{
    __shared__ __align__(16) __bf16 As[2][128*64];
    __shared__ __align__(16) __bf16 Bs[2][128*64];
    int tid = threadIdx.x;
    int m0 = blockIdx.y * 128, n0 = blockIdx.x * 128;
    int wave = tid >> 6, lane = tid & 63, lr = lane & 15, lk = lane >> 4;
    int wr = wave >> 1, wc = wave & 1;

    // per-thread staging geometry (4 units each of A,B per K-step)
    int ur[4], uc[4];
    #pragma unroll
    for (int i = 0; i < 4; i++) {
        int u = tid + 256*i;
        ur[i] = u >> 3;
        uc[i] = (u & 7) ^ (ur[i] & 7);
    }

    f32x4 acc[4][4];
    f32x4 zz = {0.f, 0.f, 0.f, 0.f};
    #pragma unroll
    for (int m = 0; m < 4; m++)
        #pragma unroll
        for (int n = 0; n < 4; n++) acc[m][n] = zz;

    const int NK = K >> 6;
    // prologue: stage k-step 0 into buf 0
    #pragma unroll
    for (int i = 0; i < 4; i++) {
        int u = tid + 256*i;
        GLOAD_LDS16(&A [(size_t)(m0+ur[i])*K + uc[i]*8], &As[0][(size_t)u*8]);
        GLOAD_LDS16(&Bt[(size_t)(n0+ur[i])*K + uc[i]*8], &Bs[0][(size_t)u*8]);
    }
    __syncthreads();

    for (int ki = 0; ki < NK; ki++) {
        int cur = ki & 1;
        if (ki + 1 < NK) {
            int k1 = (ki + 1) << 6;
            int nxt = cur ^ 1;
            #pragma unroll
            for (int i = 0; i < 4; i++) {
                int u = tid + 256*i;
                GLOAD_LDS16(&A [(size_t)(m0+ur[i])*K + k1 + uc[i]*8], &As[nxt][(size_t)u*8]);
                GLOAD_LDS16(&Bt[(size_t)(n0+ur[i])*K + k1 + uc[i]*8], &Bs[nxt][(size_t)u*8]);
            }
        }
        const char* ab = (const char*)&As[cur][0];
        const char* bb = (const char*)&Bs[cur][0];
        #pragma unroll
        for (int kk = 0; kk < 2; kk++) {
            bf16x8 af[4], bfr[4];
            #pragma unroll
            for (int m = 0; m < 4; m++) {
                int row = wr*64 + m*16 + lr;
                int byte = (row*128 + kk*64 + lk*16) ^ ((row & 7) << 4);
                af[m] = *(const bf16x8*)(ab + byte);
            }
            #pragma unroll
            for (int n = 0; n < 4; n++) {
                int row = wc*64 + n*16 + lr;
                int byte = (row*128 + kk*64 + lk*16) ^ ((row & 7) << 4);
                bfr[n] = *(const bf16x8*)(bb + byte);
            }
            #pragma unroll
            for (int m = 0; m < 4; m++)
                #pragma unroll
                for (int n = 0; n < 4; n++)
                    acc[m][n] = mfma32(af[m], bfr[n], acc[m][n]);
        }
        __syncthreads();
    }

    #pragma unroll
    for (int m = 0; m < 4; m++)
    #pragma unroll
    for (int n = 0; n < 4; n++)
    #pragma unroll
    for (int r = 0; r < 4; r++) {
        int row = m0 + wr*64 + m*16 + lk*4 + r;
        int col = n0 + wc*64 + n*16 + lr;
        float v = acc[m][n][r] + bias[col];
        if (EPI == 0) {
            Cout[(size_t)row * N + col] = v;
        } else {
            int b_idx = row >> 11, s = row & 2047;
            int which = col / HID, hc = col % HID;
            int bh = b_idx * N_HEAD + (hc >> 6);
            int d = hc & 63;
            if (which == 0)      Qo[((size_t)bh*SEQ + s)*HEAD + d] = (__bf16)(v * SC2);
            else if (which == 1) Ko[((size_t)bh*SEQ + s)*HEAD + d] = (__bf16)v;
            else                 Vo[((size_t)bh*HEAD + d)*VSTR + s] = (__bf16)v;
        }
    }
}

// ---------------- causal flash attention (LDS-shared KV, split-KV for long blocks) ----
// Block: 128 q-rows x one bh. qb>=8 blocks are SPLIT into 2 parity halves over KV
// tiles; each half writes raw partial O (bf16) + row-sums (f32); combine_split
// merges. Critical path <= 16 tiles for every block.
__global__ __launch_bounds__(256, 2) void flash_attn(
    const __bf16* __restrict__ Q, const __bf16* __restrict__ Km,
    const __bf16* __restrict__ Vt, __bf16* __restrict__ ctx,
    __bf16* __restrict__ Opart, float* __restrict__ lspart)
{
    __shared__ __align__(16) __bf16 Ks[2][64*64];
    __shared__ __align__(16) __bf16 Vs[2][64*64];
    int tid = threadIdx.x;
    int w = tid >> 6;
    int lane = tid & 63;
    int lr = lane & 15, lk = lane >> 4;
    int gid = blockIdx.x;
    int bh, qb, half, step;
    if (gid < 16*BH) {            // split blocks: qb 15..8, 2 halves each
        qb = 15 - gid / (2*BH);
        half = (gid % (2*BH)) / BH;
        bh = gid % BH;
        step = 2;
    } else {                      // unsplit: qb 7..0
        int u = gid - 16*BH;
        qb = 7 - u / BH;
        bh = u % BH;
        half = 0; step = 1;
    }
    bool split = (step == 2);
    int b_idx = bh / N_HEAD, h = bh % N_HEAD;
    int q0 = qb*128 + w*32;
    const size_t hb = (size_t)bh * SEQ * HEAD;
    const size_t vbh = (size_t)bh * HEAD * VSTR;
    f32x4 zz = {0.f, 0.f, 0.f, 0.f};

    int u0 = tid, u1 = tid + 256;
    int kr0 = u0 >> 3, kc0 = (u0 & 7) ^ (kr0 & 7);
    int kr1 = u1 >> 3, kc1 = (u1 & 7) ^ (kr1 & 7);

    bf16x8 qf0[2], qf1[2];
    #pragma unroll
    for (int kb = 0; kb < 2; kb++) {
        qf0[kb] = *(const bf16x8*)&Q[hb + (size_t)(q0 + lr)*HEAD + kb*32 + lk*8];
        qf1[kb] = *(const bf16x8*)&Q[hb + (size_t)(q0 + 16 + lr)*HEAD + kb*32 + lk*8];
    }

    f32x4 acc0[4], acc1[4];
    float ls0 = 0.f, ls1 = 0.f;
    #pragma unroll
    for (int db = 0; db < 4; db++) { acc0[db] = zz; acc1[db] = zz; }

    int nt = 2*qb + 2;
    int t0 = half;

    // prologue: stage tile t0 into buf 0
    {
        int kv = t0 * 64;
        GLOAD_LDS16(&Km[hb + (size_t)(kv+kr0)*HEAD + kc0*8],  &Ks[0][(size_t)u0*8]);
        GLOAD_LDS16(&Km[hb + (size_t)(kv+kr1)*HEAD + kc1*8],  &Ks[0][(size_t)u1*8]);
        GLOAD_LDS16(&Vt[vbh + (size_t)kr0*VSTR + kv + kc0*8], &Vs[0][(size_t)u0*8]);
        GLOAD_LDS16(&Vt[vbh + (size_t)kr1*VSTR + kv + kc1*8], &Vs[0][(size_t)u1*8]);
    }
    __syncthreads();

    int buf = 0;
    for (int t = t0; t < nt; t += step) {
        int kv0 = t * 64;
        const char* kbuf = (const char*)&Ks[buf][0];
        const char* vbuf = (const char*)&Vs[buf][0];

        if (t + step < nt) {
            int kv1 = (t + step) * 64;
            int nxt = buf ^ 1;
            GLOAD_LDS16(&Km[hb + (size_t)(kv1 + kr0)*HEAD + kc0*8],  &Ks[nxt][(size_t)u0*8]);
            GLOAD_LDS16(&Km[hb + (size_t)(kv1 + kr1)*HEAD + kc1*8],  &Ks[nxt][(size_t)u1*8]);
            GLOAD_LDS16(&Vt[vbh + (size_t)kr0*VSTR + kv1 + kc0*8],   &Vs[nxt][(size_t)u0*8]);
            GLOAD_LDS16(&Vt[vbh + (size_t)kr1*VSTR + kv1 + kc1*8],   &Vs[nxt][(size_t)u1*8]);
        }

        bf16x8 kf[4][2];
        #pragma unroll
        for (int cb = 0; cb < 4; cb++)
            #pragma unroll
            for (int kb = 0; kb < 2; kb++) {
                int row = cb*16 + lr;
                int byte = (row*128 + kb*64 + lk*16) ^ ((row & 7) << 4);
                kf[cb][kb] = *(const bf16x8*)(kbuf + byte);
            }

        bf16x8 v01[4], v23[4];
        #pragma unroll
        for (int db = 0; db < 4; db++) {
            int row = db*16 + lr;
            int rx = (row & 7) << 4;
            bf16x4 a0 = *(const bf16x4*)(vbuf + ((row*128 + lk*8)       ^ rx));
            bf16x4 a1 = *(const bf16x4*)(vbuf + ((row*128 + 32 + lk*8)  ^ rx));
            bf16x4 a2 = *(const bf16x4*)(vbuf + ((row*128 + 64 + lk*8)  ^ rx));
            bf16x4 a3 = *(const bf16x4*)(vbuf + ((row*128 + 96 + lk*8)  ^ rx));
            v01[db] = __builtin_shufflevector(a0, a1, 0,1,2,3,4,5,6,7);
            v23[db] = __builtin_shufflevector(a2, a3, 0,1,2,3,4,5,6,7);
        }

        f32x4 sc0[4], sc1[4];
        __builtin_amdgcn_s_setprio(1);
        #pragma unroll
        for (int cb = 0; cb < 4; cb++) {
            f32x4 z0 = mfma32(kf[cb][0], qf0[0], zz);
            sc0[cb] = mfma32(kf[cb][1], qf0[1], z0);
            f32x4 z1 = mfma32(kf[cb][0], qf1[0], zz);
            sc1[cb] = mfma32(kf[cb][1], qf1[1], z1);
        }
        __builtin_amdgcn_s_setprio(0);

        if (kv0 + 63 > q0) {
            #pragma unroll
            for (int cb = 0; cb < 4; cb++)
                #pragma unroll
                for (int r = 0; r < 4; r++) {
                    int kg = kv0 + cb*16 + lk*4 + r;
                    if (kg > q0 + lr)      sc0[cb][r] = -30000.f;
                    if (kg > q0 + 16 + lr) sc1[cb][r] = -30000.f;
                }
        }

        bf16x8 pa0[2], pa1[2];
        {
            float rs0 = 0.f, rs1 = 0.f;
            #pragma unroll
            for (int cb = 0; cb < 4; cb++)
                #pragma unroll
                for (int r = 0; r < 4; r++) {
                    float p0 = exp2f(sc0[cb][r]);
                    float p1 = exp2f(sc1[cb][r]);
                    rs0 += p0; rs1 += p1;
                    pa0[cb >> 1][(cb & 1)*4 + r] = (__bf16)p0;
                    pa1[cb >> 1][(cb & 1)*4 + r] = (__bf16)p1;
                }
            ls0 += rs0; ls1 += rs1;
        }

        __builtin_amdgcn_s_setprio(1);
        #pragma unroll
        for (int db = 0; db < 4; db++) {
            acc0[db] = mfma32(pa0[0], v01[db], acc0[db]);
            acc0[db] = mfma32(pa0[1], v23[db], acc0[db]);
            acc1[db] = mfma32(pa1[0], v01[db], acc1[db]);
            acc1[db] = mfma32(pa1[1], v23[db], acc1[db]);
        }
        __builtin_amdgcn_s_setprio(0);

        __syncthreads();
        buf ^= 1;
    }

    // row sums (full row, replicated)
    float rs0 = ls0;
    rs0 += __shfl_xor(rs0, 16);
    rs0 += __shfl_xor(rs0, 32);
    float rs1 = ls1;
    rs1 += __shfl_xor(rs1, 16);
    rs1 += __shfl_xor(rs1, 32);

    if (split) {
        // raw partials: O (bf16) + row sums (f32); rows are q0.. (>=1024)
        size_t ob = ((size_t)half*BH + bh) * 1024;
        #pragma unroll
        for (int db = 0; db < 4; db++)
            #pragma unroll
            for (int r = 0; r < 4; r++) {
                int d = db*16 + lr;
                int qg0 = q0 + lk*4 + r;
                int qg1 = q0 + 16 + lk*4 + r;
                Opart[(ob + qg0 - 1024)*64 + d] = (__bf16)acc0[db][r];
                Opart[(ob + qg1 - 1024)*64 + d] = (__bf16)acc1[db][r];
            }
        if (lk == 0) {
            lspart[(size_t)half*BH*1024 + (size_t)bh*1024 + (q0 + lr - 1024)]      = rs0;
            lspart[(size_t)half*BH*1024 + (size_t)bh*1024 + (q0 + 16 + lr - 1024)] = rs1;
        }
        return;
    }

    float rl0 = 1.0f / rs0, rl1 = 1.0f / rs1;
    float li0[4], li1[4];
    #pragma unroll
    for (int r = 0; r < 4; r++) {
        li0[r] = __shfl(rl0, (lane & 48) | (lk*4 + r));
        li1[r] = __shfl(rl1, (lane & 48) | (lk*4 + r));
    }
    #pragma unroll
    for (int db = 0; db < 4; db++)
        #pragma unroll
        for (int r = 0; r < 4; r++) {
            int d = db*16 + lr;
            int qg0 = q0 + lk*4 + r;
            int qg1 = q0 + 16 + lk*4 + r;
            ctx[((size_t)(b_idx*SEQ + qg0))*HID + h*HEAD + d] = (__bf16)(acc0[db][r] * li0[r]);
            ctx[((size_t)(b_idx*SEQ + qg1))*HID + h*HEAD + d] = (__bf16)(acc1[db][r] * li1[r]);
        }
}

// ---------------- combine split-KV partials (rows 1024..2047 of each bh) -------------
__global__ __launch_bounds__(256) void combine_split(
    const __bf16* __restrict__ Opart, const float* __restrict__ lspart,
    __bf16* __restrict__ ctx)
{
    int i = blockIdx.x * 256 + threadIdx.x;   // 24*1024*8 = 196608
    int row = i >> 3, dc = i & 7;
    int bh = row >> 10, sl = row & 1023;
    int b_idx = bh / N_HEAD, h = bh % N_HEAD;
    bf16x8 o0 = *(const bf16x8*)&Opart[(((size_t)0*BH + bh)*1024 + sl)*64 + dc*8];
    bf16x8 o1 = *(const bf16x8*)&Opart[(((size_t)1*BH + bh)*1024 + sl)*64 + dc*8];
    float ls = lspart[(size_t)bh*1024 + sl] + lspart[(size_t)BH*1024 + (size_t)bh*1024 + sl];
    float rl = 1.0f / ls;
    bf16x8 o;
    #pragma unroll
    for (int j = 0; j < 8; j++) o[j] = (__bf16)(((float)o0[j] + (float)o1[j]) * rl);
    *(bf16x8*)&ctx[((size_t)(b_idx*SEQ + 1024 + sl))*HID + h*HEAD + dc*8] = o;
}

// ---------------- launch ----------------
extern "C" void kernel_launch(void* const* d_in, const int* in_sizes, int n_in,
                              void* d_out, int out_size, void* d_ws, size_t ws_size,
                              hipStream_t stream) {
    const float* x  = (const float*)d_in[0];   // [2,2048,768]
    const float* w1 = (const float*)d_in[1];   // [768,2304]
    const float* b1 = (const float*)d_in[2];   // [2304]
    const float* w2 = (const float*)d_in[3];   // [768,768]
    const float* b2 = (const float*)d_in[4];   // [768]
    float* out = (float*)d_out;

    char* ws = (char*)d_ws;
    size_t o = 0;
    __bf16* Xb  = (__bf16*)(ws + o); o += (size_t)MROWS*HID*2;       // reused as Opart after gemm1
    __bf16* W1t = (__bf16*)(ws + o); o += (size_t)3*HID*HID*2;       // reused as lspart after gemm1
    __bf16* W2t = (__bf16*)(ws + o); o += (size_t)HID*HID*2;
    __bf16* Qb  = (__bf16*)(ws + o); o += (size_t)MROWS*HID*2;
    __bf16* Kb  = (__bf16*)(ws + o); o += (size_t)MROWS*HID*2;
    __bf16* Vt  = (__bf16*)(ws + o); o += (size_t)BH*HEAD*VSTR*2;
    __bf16* CTX = (__bf16*)(ws + o); o += (size_t)MROWS*HID*2;

    __bf16* Opart  = Xb;               // 2*24*1024*64 bf16 = 6.29 MB (== Xb size)
    float*  lspart = (float*)W1t;      // 2*24*1024 f32 = 196 KB

    cast_f32_bf16<<<(MROWS*HID/8 + 255)/256, 256, 0, stream>>>(x, Xb, MROWS*HID/8);
    transpose_cast<<<dim3(3*HID/32, HID/32), dim3(32, 8), 0, stream>>>(w1, W1t, HID, 3*HID);
    transpose_cast<<<dim3(HID/32,   HID/32), dim3(32, 8), 0, stream>>>(w2, W2t, HID, HID);

    gemm_bt<1><<<dim3(3*HID/128, MROWS/128), 256, 0, stream>>>(
        Xb, W1t, b1, nullptr, Qb, Kb, Vt, MROWS, 3*HID, HID);

    flash_attn<<<dim3(24*BH), 256, 0, stream>>>(Qb, Kb, Vt, CTX, Opart, lspart);
    combine_split<<<dim3(BH*1024*8/256), 256, 0, stream>>>(Opart, lspart, CTX);

    gemm_bt<0><<<dim3(HID/128, MROWS/128), 256, 0, stream>>>(
        CTX, W2t, b2, out, nullptr, nullptr, nullptr, MROWS, HID, HID);
}